// Round 7
// baseline (225.014 us; speedup 1.0000x reference)
//
#include <hip/hip_runtime.h>
#include <math.h>

#define N_TOK 16384
#define D_DIM 1024
#define E_NUM 8
#define H_DIM 256
#define LN_EPS 1e-5f

#define BM 128
#define BN1 128          /* N-tile GEMM1 (was 64; halves A re-reads) */
#define BN2 128          /* N-tile GEMM2 */
#define BKG 64           /* K-tile for both GEMMs */
#define MAXTILES (N_TOK / BM + E_NUM)   /* 136 */
#define MP (MAXTILES * BM)              /* 17408 */
#define CSTRIDE 16       /* cnt[k*CSTRIDE]: 64 B apart -> separate L2 lines */

typedef __attribute__((ext_vector_type(8))) short bf16x8;
typedef __attribute__((ext_vector_type(4))) float f32x4;

__device__ __forceinline__ unsigned short f2bf(float f) {
  union { float f; unsigned u; } cv; cv.f = f;
  unsigned u = cv.u;
  u += 0x7fffu + ((u >> 16) & 1u);   // round-to-nearest-even
  return (unsigned short)(u >> 16);
}

__device__ __forceinline__ void gl_lds16(const void* g, void* l) {
  __builtin_amdgcn_global_load_lds(
      (const __attribute__((address_space(1))) unsigned int*)g,
      (__attribute__((address_space(3))) unsigned int*)l, 16, 0, 0);
}

// fast erf via Abramowitz-Stegun 7.1.26 (|err| <= 1.5e-7) + hw exp.
__device__ __forceinline__ float gelu_exact_fast(float v) {
  float u = fabsf(v) * 0.70710678118654752f;
  float t = 1.0f / (1.0f + 0.3275911f * u);
  float poly = t * (0.254829592f + t * (-0.284496736f + t * (1.421413741f
             + t * (-1.453152027f + t * 1.061405429f))));
  float er = 1.0f - poly * __expf(-u * u);
  er = v >= 0.0f ? er : -er;
  return 0.5f * v * (1.0f + er);
}

// ---- VALU cross-lane transport (DPP) + verified ds_swizzle patterns --------
template <int CTRL>
__device__ __forceinline__ int dppi(int x) {
  return __builtin_amdgcn_update_dpp(0, x, CTRL, 0xf, 0xf, true);
}
template <int CTRL>
__device__ __forceinline__ double dppd(double x) {
  union { double d; int i[2]; } u; u.d = x;
  u.i[0] = dppi<CTRL>(u.i[0]);
  u.i[1] = dppi<CTRL>(u.i[1]);
  return u.d;
}
template <int CTRL>
__device__ __forceinline__ float dppf(float x) {
  union { float f; int i; } u; u.f = x;
  u.i = dppi<CTRL>(u.i);
  return u.f;
}
template <int IMM>
__device__ __forceinline__ double swzd(double x) {
  union { double d; int i[2]; } u; u.d = x;
  u.i[0] = __builtin_amdgcn_ds_swizzle(u.i[0], IMM);
  u.i[1] = __builtin_amdgcn_ds_swizzle(u.i[1], IMM);
  return u.d;
}
template <int IMM>
__device__ __forceinline__ float swzf(float x) {
  union { float f; int i; } u; u.f = x;
  u.i = __builtin_amdgcn_ds_swizzle(u.i, IMM);
  return u.f;
}

// ---------------- gate + fused scatter: ONE WAVE PER TOKEN ------------------
// Scatter placed AFTER the xhat write loop (v[] dead) to keep VGPR at 64.
__global__ __launch_bounds__(256) void smoe_gate(
    const float* __restrict__ x, const float* __restrict__ wg,
    const float* __restrict__ ln_s, const float* __restrict__ ln_b,
    unsigned short* __restrict__ xhat,
    int* __restrict__ cnt, int* __restrict__ tokp)
{
  int lane = threadIdx.x & 63, wave = threadIdx.x >> 6;
  int t = blockIdx.x * 4 + wave;

  const float4* x4 = (const float4*)x + (size_t)t * 256;
  float4 v[4];
  float s = 0.f, ss = 0.f;
#pragma unroll
  for (int j = 0; j < 4; j++) {
    v[j] = x4[lane + 64 * j];
    s  += v[j].x + v[j].y + v[j].z + v[j].w;
    ss += v[j].x * v[j].x + v[j].y * v[j].y + v[j].z * v[j].z + v[j].w * v[j].w;
  }
  const float4* wg4 = (const float4*)wg;
  double lg[E_NUM];
#pragma unroll
  for (int e = 0; e < E_NUM; e++) {
    double acc = 0.0;
#pragma unroll
    for (int j = 0; j < 4; j++) {
      float4 w = wg4[e * 256 + lane + 64 * j];
      acc += (double)v[j].x * w.x + (double)v[j].y * w.y
           + (double)v[j].z * w.z + (double)v[j].w * w.w;
    }
    lg[e] = acc;
  }

  double a0, a1, a2, a3;
  {
    double p0 = dppd<0xB1>(lg[0]), p1 = dppd<0xB1>(lg[1]);
    double p2 = dppd<0xB1>(lg[2]), p3 = dppd<0xB1>(lg[3]);
    double p4 = dppd<0xB1>(lg[4]), p5 = dppd<0xB1>(lg[5]);
    double p6 = dppd<0xB1>(lg[6]), p7 = dppd<0xB1>(lg[7]);
    bool b = lane & 1;
    a0 = b ? lg[1] + p1 : lg[0] + p0;
    a1 = b ? lg[3] + p3 : lg[2] + p2;
    a2 = b ? lg[5] + p5 : lg[4] + p4;
    a3 = b ? lg[7] + p7 : lg[6] + p6;
  }
  double c0, c1;
  {
    double q0 = dppd<0x4E>(a0), q1 = dppd<0x4E>(a1);
    double q2 = dppd<0x4E>(a2), q3 = dppd<0x4E>(a3);
    bool b = (lane >> 1) & 1;
    c0 = b ? a1 + q1 : a0 + q0;
    c1 = b ? a3 + q3 : a2 + q2;
  }
  double c;
  {
    double r0 = swzd<0x101F>(c0), r1 = swzd<0x101F>(c1);   // TRUE xor4
    bool b = (lane >> 2) & 1;
    c = b ? c1 + r1 : c0 + r0;
  }
  c += dppd<0x128>(c);          // xor8
  c += swzd<0x401F>(c);         // xor16
  c += __shfl_xor(c, 32, 64);   // xor32

  double val = c; int idx = lane & 7;
  {
    double ov = dppd<0xB1>(val); int oi = dppi<0xB1>(idx);
    if (ov > val || (ov == val && oi < idx)) { val = ov; idx = oi; }
  }
  {
    double ov = dppd<0x4E>(val); int oi = dppi<0x4E>(idx);
    if (ov > val || (ov == val && oi < idx)) { val = ov; idx = oi; }
  }
  {
    double ov = dppd<0x124>(val); int oi = dppi<0x124>(idx);
    if (ov > val || (ov == val && oi < idx)) { val = ov; idx = oi; }
  }
  int best = idx;

  s += dppf<0xB1>(s);   ss += dppf<0xB1>(ss);
  s += dppf<0x4E>(s);   ss += dppf<0x4E>(ss);
  s += dppf<0x141>(s);  ss += dppf<0x141>(ss);
  s += dppf<0x128>(s);  ss += dppf<0x128>(ss);
  s += swzf<0x401F>(s); ss += swzf<0x401F>(ss);
  s += __shfl_xor(s, 32, 64);
  ss += __shfl_xor(ss, 32, 64);

  float mean = s * (1.0f / (float)D_DIM);
  float var  = ss * (1.0f / (float)D_DIM) - mean * mean;
  float rstd = 1.0f / sqrtf(var + LN_EPS);

  const float4* s4 = (const float4*)(ln_s + (size_t)best * D_DIM);
  const float4* b4 = (const float4*)(ln_b + (size_t)best * D_DIM);
  ushort4* xo = (ushort4*)(xhat + (size_t)t * D_DIM);
#pragma unroll
  for (int j = 0; j < 4; j++) {
    float4 sc = s4[lane + 64 * j], bi = b4[lane + 64 * j];
    ushort4 o;
    o.x = f2bf((v[j].x - mean) * rstd * sc.x + bi.x);
    o.y = f2bf((v[j].y - mean) * rstd * sc.y + bi.y);
    o.z = f2bf((v[j].z - mean) * rstd * sc.z + bi.z);
    o.w = f2bf((v[j].w - mean) * rstd * sc.w + bi.w);
    xo[lane + 64 * j] = o;
  }

  // fused scatter: one atomic per token, after v[] is dead (VGPR-safe).
  if (lane == 0) {
    int pos = atomicAdd(&cnt[best * CSTRIDE], 1);
    tokp[best * N_TOK + pos] = t;
  }
}

// ---------------- weight transpose-convert (pure, 1024 blocks) ---------------
__global__ __launch_bounds__(256) void smoe_cvt(
    const float* __restrict__ w1, unsigned short* __restrict__ w1t,
    const float* __restrict__ w2, unsigned short* __restrict__ w2t)
{
  int bid = blockIdx.x;                // 0..1023
  const float* in; unsigned short* out; int R, C;
  if (bid < 512) { in = w1; out = w1t; R = D_DIM; C = H_DIM; }
  else           { in = w2; out = w2t; R = H_DIM; C = D_DIM; bid -= 512; }
  int rt = R / 64, ct = C / 64;
  int e = bid / (rt * ct);
  int rem = bid % (rt * ct);
  int r0 = (rem / ct) * 64, c0 = (rem % ct) * 64;
  __shared__ float tile[64][65];
  int tx = threadIdx.x & 63, ty = threadIdx.x >> 6;   // ty 0..3
  const float* src = in + (size_t)e * R * C;
#pragma unroll
  for (int i = 0; i < 16; i++)
    tile[ty + 4 * i][tx] = src[(size_t)(r0 + ty + 4 * i) * C + c0 + tx];
  __syncthreads();
  unsigned short* dst = out + (size_t)e * R * C;
#pragma unroll
  for (int i = 0; i < 16; i++)
    dst[(size_t)(c0 + ty + 4 * i) * R + r0 + tx] = f2bf(tile[tx][ty + 4 * i]);
}

// ---- per-block tile->expert mapping derived from the 8 counts --------------
__device__ __forceinline__ void tile_map(const int* __restrict__ cnt, int mt,
                                         int& e, int& loc, int& ccnt) {
  int tb = 0; e = 0; loc = -1; ccnt = 0;
#pragma unroll
  for (int k = 0; k < E_NUM; k++) {
    int ck = cnt[k * CSTRIDE];
    int ntk = (ck + BM - 1) >> 7;
    if (mt >= tb && mt < tb + ntk) { e = k; loc = (mt - tb) * BM; ccnt = ck; }
    tb += ntk;
  }
}

// ---------------- GEMM1: h = gelu(xhat_gathered @ W1t^T + b1), bf16 out ------
// 128x128 tile (BN 64->128: halves A re-reads), BK=64, swizzle + DMA dbuf.
__global__ __launch_bounds__(256) void smoe_gemm1(
    const unsigned short* __restrict__ xhat,   // [N][D]
    const unsigned short* __restrict__ w1t,    // [E][H][D]
    const float* __restrict__ b1,              // [E][H]
    const int* __restrict__ cnt,
    const int* __restrict__ tokp,              // [E][N_TOK]
    unsigned short* __restrict__ hbuf)         // [MP][H]
{
  int mt = blockIdx.x;
  int e, loc, ccnt;
  tile_map(cnt, mt, e, loc, ccnt);
  if (loc < 0) return;
  int nt = blockIdx.y;                 // 0..1 over H
  int tid = threadIdx.x;
  __shared__ unsigned short As[2][BM * BKG];    // 2 x 16 KB
  __shared__ unsigned short Bs[2][BN1 * BKG];   // 2 x 16 KB  (64 KB total)

  int r8 = tid >> 3;                   // 0..31
  int c8 = tid & 7;
  int slot = c8 ^ (r8 & 7);            // inverse-swizzled source slot

  const unsigned short* asrc[4];
#pragma unroll
  for (int j = 0; j < 4; j++) {
    int rl = loc + r8 + 32 * j;
    int tok = rl < ccnt ? tokp[e * N_TOK + rl] : 0;
    asrc[j] = xhat + (size_t)tok * D_DIM + slot * 8;
  }
  const unsigned short* bsrc[4];
#pragma unroll
  for (int j = 0; j < 4; j++)
    bsrc[j] = w1t + (size_t)e * H_DIM * D_DIM
            + (size_t)(nt * BN1 + r8 + 32 * j) * D_DIM + slot * 8;

  int wave = tid >> 6, lane = tid & 63;
  int wr = (wave >> 1) * 64;
  int wc = (wave & 1) * 64;
  int qm = lane & 15, quad = lane >> 4;

  int arow[4], brow[4], soff[2];
#pragma unroll
  for (int mi = 0; mi < 4; mi++) arow[mi] = (wr + mi * 16 + qm) * BKG;
#pragma unroll
  for (int ni = 0; ni < 4; ni++) brow[ni] = (wc + ni * 16 + qm) * BKG;
#pragma unroll
  for (int kk = 0; kk < 2; kk++) soff[kk] = ((kk * 4 + quad) ^ (qm & 7)) * 8;

  f32x4 acc[4][4] = {};
  int cur = 0;

#pragma unroll
  for (int j = 0; j < 4; j++) gl_lds16(asrc[j], &As[0][j * 2048 + tid * 8]);
#pragma unroll
  for (int j = 0; j < 4; j++) gl_lds16(bsrc[j], &Bs[0][j * 2048 + tid * 8]);
  __syncthreads();

  for (int t = 0; t < D_DIM / BKG; ++t) {       // 16 steps
    if (t + 1 < D_DIM / BKG) {
      int k0 = (t + 1) * BKG;
      int nb = cur ^ 1;
#pragma unroll
      for (int j = 0; j < 4; j++) gl_lds16(asrc[j] + k0, &As[nb][j * 2048 + tid * 8]);
#pragma unroll
      for (int j = 0; j < 4; j++) gl_lds16(bsrc[j] + k0, &Bs[nb][j * 2048 + tid * 8]);
    }
    bf16x8 af[2][4], bfr[2][4];
#pragma unroll
    for (int kk = 0; kk < 2; kk++) {
#pragma unroll
      for (int mi = 0; mi < 4; mi++)
        af[kk][mi] = *(const bf16x8*)&As[cur][arow[mi] + soff[kk]];
#pragma unroll
      for (int ni = 0; ni < 4; ni++)
        bfr[kk][ni] = *(const bf16x8*)&Bs[cur][brow[ni] + soff[kk]];
    }
#pragma unroll
    for (int kk = 0; kk < 2; kk++)
#pragma unroll
      for (int mi = 0; mi < 4; mi++)
#pragma unroll
        for (int ni = 0; ni < 4; ni++)
          acc[mi][ni] = __builtin_amdgcn_mfma_f32_16x16x32_bf16(
              af[kk][mi], bfr[kk][ni], acc[mi][ni], 0, 0, 0);
    __syncthreads();
    cur ^= 1;
  }

  int mbase = mt * BM;
#pragma unroll
  for (int ni = 0; ni < 4; ni++) {
    int col = nt * BN1 + wc + ni * 16 + qm;
    float bias = b1[e * H_DIM + col];
#pragma unroll
    for (int mi = 0; mi < 4; mi++) {
      int rl = wr + mi * 16 + quad * 4;
#pragma unroll
      for (int i = 0; i < 4; i++) {
        float g = gelu_exact_fast(acc[mi][ni][i] + bias);
        hbuf[(size_t)(mbase + rl + i) * H_DIM + col] = f2bf(g);
      }
    }
  }
}

// ---------------- GEMM2: y[tok] = h @ W2t^T + b2, fp32 scatter ----------------
__global__ __launch_bounds__(256) void smoe_gemm2(
    const unsigned short* __restrict__ hbuf,   // [MP][H]
    const unsigned short* __restrict__ w2t,    // [E][D][H]
    const float* __restrict__ b2,              // [E][D]
    const int* __restrict__ cnt,
    const int* __restrict__ tokp,              // [E][N_TOK]
    float* __restrict__ y)                     // [N][D]
{
  int mt = blockIdx.x;
  int e, loc, ccnt;
  tile_map(cnt, mt, e, loc, ccnt);
  if (loc < 0) return;
  int nt = blockIdx.y;                 // 0..7 over D
  int tid = threadIdx.x;
  __shared__ unsigned short As[2][BM * BKG];    // 2 x 16 KB
  __shared__ unsigned short Bs[2][BN2 * BKG];   // 2 x 16 KB  (64 KB total)

  int r8 = tid >> 3;
  int c8 = tid & 7;
  int slot = c8 ^ (r8 & 7);

  const unsigned short* asrc[4];
#pragma unroll
  for (int j = 0; j < 4; j++)
    asrc[j] = hbuf + (size_t)(mt * BM + r8 + 32 * j) * H_DIM + slot * 8;
  const unsigned short* bsrc[4];
#pragma unroll
  for (int j = 0; j < 4; j++)
    bsrc[j] = w2t + (size_t)e * D_DIM * H_DIM
            + (size_t)(nt * BN2 + r8 + 32 * j) * H_DIM + slot * 8;

  int wave = tid >> 6, lane = tid & 63;
  int wr = (wave >> 1) * 64;
  int wc = (wave & 1) * 64;
  int qm = lane & 15, quad = lane >> 4;

  int arow[4], brow[4], soff[2];
#pragma unroll
  for (int mi = 0; mi < 4; mi++) arow[mi] = (wr + mi * 16 + qm) * BKG;
#pragma unroll
  for (int ni = 0; ni < 4; ni++) brow[ni] = (wc + ni * 16 + qm) * BKG;
#pragma unroll
  for (int kk = 0; kk < 2; kk++) soff[kk] = ((kk * 4 + quad) ^ (qm & 7)) * 8;

  f32x4 acc[4][4] = {};
  int cur = 0;

#pragma unroll
  for (int j = 0; j < 4; j++) gl_lds16(asrc[j], &As[0][j * 2048 + tid * 8]);
#pragma unroll
  for (int j = 0; j < 4; j++) gl_lds16(bsrc[j], &Bs[0][j * 2048 + tid * 8]);
  __syncthreads();

  for (int t = 0; t < H_DIM / BKG; ++t) {       // 4 steps
    if (t + 1 < H_DIM / BKG) {
      int k0 = (t + 1) * BKG;
      int nb = cur ^ 1;
#pragma unroll
      for (int j = 0; j < 4; j++) gl_lds16(asrc[j] + k0, &As[nb][j * 2048 + tid * 8]);
#pragma unroll
      for (int j = 0; j < 4; j++) gl_lds16(bsrc[j] + k0, &Bs[nb][j * 2048 + tid * 8]);
    }
    bf16x8 af[2][4], bfr[2][4];
#pragma unroll
    for (int kk = 0; kk < 2; kk++) {
#pragma unroll
      for (int mi = 0; mi < 4; mi++)
        af[kk][mi] = *(const bf16x8*)&As[cur][arow[mi] + soff[kk]];
#pragma unroll
      for (int ni = 0; ni < 4; ni++)
        bfr[kk][ni] = *(const bf16x8*)&Bs[cur][brow[ni] + soff[kk]];
    }
#pragma unroll
    for (int kk = 0; kk < 2; kk++)
#pragma unroll
      for (int mi = 0; mi < 4; mi++)
#pragma unroll
        for (int ni = 0; ni < 4; ni++)
          acc[mi][ni] = __builtin_amdgcn_mfma_f32_16x16x32_bf16(
              af[kk][mi], bfr[kk][ni], acc[mi][ni], 0, 0, 0);
    __syncthreads();
    cur ^= 1;
  }

#pragma unroll
  for (int mi = 0; mi < 4; mi++) {
#pragma unroll
    for (int i = 0; i < 4; i++) {
      int rl = loc + wr + mi * 16 + quad * 4 + i;
      if (rl >= ccnt) continue;
      int tok = tokp[e * N_TOK + rl];
#pragma unroll
      for (int ni = 0; ni < 4; ni++) {
        int col = nt * BN2 + wc + ni * 16 + qm;
        y[(size_t)tok * D_DIM + col] = acc[mi][ni][i] + b2[e * D_DIM + col];
      }
    }
  }
}

extern "C" void kernel_launch(void* const* d_in, const int* in_sizes, int n_in,
                              void* d_out, int out_size, void* d_ws, size_t ws_size,
                              hipStream_t stream) {
  (void)in_sizes; (void)n_in; (void)out_size; (void)ws_size;
  const float* x    = (const float*)d_in[0];
  const float* wg   = (const float*)d_in[1];
  const float* ln_s = (const float*)d_in[2];
  const float* ln_b = (const float*)d_in[3];
  const float* w1   = (const float*)d_in[4];
  const float* b1   = (const float*)d_in[5];
  const float* w2   = (const float*)d_in[6];
  const float* b2   = (const float*)d_in[7];
  float* y = (float*)d_out;

  char* ws = (char*)d_ws;
  size_t off = 0;
  auto alloc = [&](size_t bytes) {
    void* p = ws + off;
    off = (off + bytes + 255) & ~(size_t)255;
    return p;
  };
  unsigned short* xhat = (unsigned short*)alloc((size_t)N_TOK * D_DIM * 2);          // 32 MB
  unsigned short* w1t  = (unsigned short*)alloc((size_t)E_NUM * D_DIM * H_DIM * 2);  // 4 MB
  unsigned short* w2t  = (unsigned short*)alloc((size_t)E_NUM * D_DIM * H_DIM * 2);  // 4 MB
  unsigned short* hbuf = (unsigned short*)alloc((size_t)MP * H_DIM * 2);             // 8.5 MB
  int* tokp   = (int*)alloc((size_t)E_NUM * N_TOK * 4);                              // 512 KB
  int* cnt    = (int*)alloc((size_t)E_NUM * CSTRIDE * 4);                            // 512 B

  hipMemsetAsync(cnt, 0, (size_t)E_NUM * CSTRIDE * 4, stream);
  smoe_gate<<<N_TOK / 4, 256, 0, stream>>>(x, wg, ln_s, ln_b, xhat, cnt, tokp);
  smoe_cvt<<<1024, 256, 0, stream>>>(w1, w1t, w2, w2t);
  smoe_gemm1<<<dim3(MAXTILES, H_DIM / BN1), 256, 0, stream>>>(xhat, w1t, b1, cnt, tokp, hbuf);
  smoe_gemm2<<<dim3(MAXTILES, D_DIM / BN2), 256, 0, stream>>>(hbuf, w2t, b2, cnt, tokp, y);
}

// Round 8
// 212.429 us; speedup vs baseline: 1.0592x; 1.0592x over previous
//
#include <hip/hip_runtime.h>
#include <math.h>

#define N_TOK 16384
#define D_DIM 1024
#define E_NUM 8
#define H_DIM 256
#define LN_EPS 1e-5f

#define BM 128
#define BN1 64           /* N-tile GEMM1 (48KB LDS -> 3 blocks/CU) */
#define BN2 64           /* N-tile GEMM2 (was 128; 48KB LDS -> 3 blocks/CU) */
#define BKG 64           /* K-tile for both GEMMs */
#define MAXTILES (N_TOK / BM + E_NUM)   /* 136 */
#define MP (MAXTILES * BM)              /* 17408 */
#define CSTRIDE 16       /* cnt[k*CSTRIDE]: 64 B apart -> separate L2 lines */

typedef __attribute__((ext_vector_type(8))) short bf16x8;
typedef __attribute__((ext_vector_type(4))) float f32x4;

__device__ __forceinline__ unsigned short f2bf(float f) {
  union { float f; unsigned u; } cv; cv.f = f;
  unsigned u = cv.u;
  u += 0x7fffu + ((u >> 16) & 1u);   // round-to-nearest-even
  return (unsigned short)(u >> 16);
}

__device__ __forceinline__ void gl_lds16(const void* g, void* l) {
  __builtin_amdgcn_global_load_lds(
      (const __attribute__((address_space(1))) unsigned int*)g,
      (__attribute__((address_space(3))) unsigned int*)l, 16, 0, 0);
}

// fast erf via Abramowitz-Stegun 7.1.26 (|err| <= 1.5e-7) + hw exp.
__device__ __forceinline__ float gelu_exact_fast(float v) {
  float u = fabsf(v) * 0.70710678118654752f;
  float t = 1.0f / (1.0f + 0.3275911f * u);
  float poly = t * (0.254829592f + t * (-0.284496736f + t * (1.421413741f
             + t * (-1.453152027f + t * 1.061405429f))));
  float er = 1.0f - poly * __expf(-u * u);
  er = v >= 0.0f ? er : -er;
  return 0.5f * v * (1.0f + er);
}

// ---- VALU cross-lane transport (DPP) + verified ds_swizzle patterns --------
template <int CTRL>
__device__ __forceinline__ int dppi(int x) {
  return __builtin_amdgcn_update_dpp(0, x, CTRL, 0xf, 0xf, true);
}
template <int CTRL>
__device__ __forceinline__ double dppd(double x) {
  union { double d; int i[2]; } u; u.d = x;
  u.i[0] = dppi<CTRL>(u.i[0]);
  u.i[1] = dppi<CTRL>(u.i[1]);
  return u.d;
}
template <int CTRL>
__device__ __forceinline__ float dppf(float x) {
  union { float f; int i; } u; u.f = x;
  u.i = dppi<CTRL>(u.i);
  return u.f;
}
template <int IMM>
__device__ __forceinline__ double swzd(double x) {
  union { double d; int i[2]; } u; u.d = x;
  u.i[0] = __builtin_amdgcn_ds_swizzle(u.i[0], IMM);
  u.i[1] = __builtin_amdgcn_ds_swizzle(u.i[1], IMM);
  return u.d;
}
template <int IMM>
__device__ __forceinline__ float swzf(float x) {
  union { float f; int i; } u; u.f = x;
  u.i = __builtin_amdgcn_ds_swizzle(u.i, IMM);
  return u.f;
}

// ---------------- gate: ONE WAVE PER TOKEN (round-6 proven, 64 VGPR) ---------
__global__ __launch_bounds__(256) void smoe_gate(
    const float* __restrict__ x, const float* __restrict__ wg,
    const float* __restrict__ ln_s, const float* __restrict__ ln_b,
    unsigned short* __restrict__ xhat, int* __restrict__ eid)
{
  int lane = threadIdx.x & 63, wave = threadIdx.x >> 6;
  int t = blockIdx.x * 4 + wave;

  const float4* x4 = (const float4*)x + (size_t)t * 256;
  float4 v[4];
  float s = 0.f, ss = 0.f;
#pragma unroll
  for (int j = 0; j < 4; j++) {
    v[j] = x4[lane + 64 * j];
    s  += v[j].x + v[j].y + v[j].z + v[j].w;
    ss += v[j].x * v[j].x + v[j].y * v[j].y + v[j].z * v[j].z + v[j].w * v[j].w;
  }
  const float4* wg4 = (const float4*)wg;
  double lg[E_NUM];
#pragma unroll
  for (int e = 0; e < E_NUM; e++) {
    double acc = 0.0;
#pragma unroll
    for (int j = 0; j < 4; j++) {
      float4 w = wg4[e * 256 + lane + 64 * j];
      acc += (double)v[j].x * w.x + (double)v[j].y * w.y
           + (double)v[j].z * w.z + (double)v[j].w * w.w;
    }
    lg[e] = acc;
  }

  double a0, a1, a2, a3;
  {
    double p0 = dppd<0xB1>(lg[0]), p1 = dppd<0xB1>(lg[1]);
    double p2 = dppd<0xB1>(lg[2]), p3 = dppd<0xB1>(lg[3]);
    double p4 = dppd<0xB1>(lg[4]), p5 = dppd<0xB1>(lg[5]);
    double p6 = dppd<0xB1>(lg[6]), p7 = dppd<0xB1>(lg[7]);
    bool b = lane & 1;
    a0 = b ? lg[1] + p1 : lg[0] + p0;
    a1 = b ? lg[3] + p3 : lg[2] + p2;
    a2 = b ? lg[5] + p5 : lg[4] + p4;
    a3 = b ? lg[7] + p7 : lg[6] + p6;
  }
  double c0, c1;
  {
    double q0 = dppd<0x4E>(a0), q1 = dppd<0x4E>(a1);
    double q2 = dppd<0x4E>(a2), q3 = dppd<0x4E>(a3);
    bool b = (lane >> 1) & 1;
    c0 = b ? a1 + q1 : a0 + q0;
    c1 = b ? a3 + q3 : a2 + q2;
  }
  double c;
  {
    double r0 = swzd<0x101F>(c0), r1 = swzd<0x101F>(c1);   // TRUE xor4
    bool b = (lane >> 2) & 1;
    c = b ? c1 + r1 : c0 + r0;
  }
  c += dppd<0x128>(c);          // xor8
  c += swzd<0x401F>(c);         // xor16
  c += __shfl_xor(c, 32, 64);   // xor32

  double val = c; int idx = lane & 7;
  {
    double ov = dppd<0xB1>(val); int oi = dppi<0xB1>(idx);
    if (ov > val || (ov == val && oi < idx)) { val = ov; idx = oi; }
  }
  {
    double ov = dppd<0x4E>(val); int oi = dppi<0x4E>(idx);
    if (ov > val || (ov == val && oi < idx)) { val = ov; idx = oi; }
  }
  {
    double ov = dppd<0x124>(val); int oi = dppi<0x124>(idx);
    if (ov > val || (ov == val && oi < idx)) { val = ov; idx = oi; }
  }
  int best = idx;

  s += dppf<0xB1>(s);   ss += dppf<0xB1>(ss);
  s += dppf<0x4E>(s);   ss += dppf<0x4E>(ss);
  s += dppf<0x141>(s);  ss += dppf<0x141>(ss);
  s += dppf<0x128>(s);  ss += dppf<0x128>(ss);
  s += swzf<0x401F>(s); ss += swzf<0x401F>(ss);
  s += __shfl_xor(s, 32, 64);
  ss += __shfl_xor(ss, 32, 64);

  float mean = s * (1.0f / (float)D_DIM);
  float var  = ss * (1.0f / (float)D_DIM) - mean * mean;
  float rstd = 1.0f / sqrtf(var + LN_EPS);

  if (lane == 0) eid[t] = best;

  const float4* s4 = (const float4*)(ln_s + (size_t)best * D_DIM);
  const float4* b4 = (const float4*)(ln_b + (size_t)best * D_DIM);
  ushort4* xo = (ushort4*)(xhat + (size_t)t * D_DIM);
#pragma unroll
  for (int j = 0; j < 4; j++) {
    float4 sc = s4[lane + 64 * j], bi = b4[lane + 64 * j];
    ushort4 o;
    o.x = f2bf((v[j].x - mean) * rstd * sc.x + bi.x);
    o.y = f2bf((v[j].y - mean) * rstd * sc.y + bi.y);
    o.z = f2bf((v[j].z - mean) * rstd * sc.z + bi.z);
    o.w = f2bf((v[j].w - mean) * rstd * sc.w + bi.w);
    xo[lane + 64 * j] = o;
  }
}

// ---------------- scatter (blocks 0..63) + weight cvt (blocks 64..1087) -------
__global__ __launch_bounds__(256) void smoe_scatter_cvt(
    const int* __restrict__ eid, int* __restrict__ cnt, int* __restrict__ tokp,
    const float* __restrict__ w1, unsigned short* __restrict__ w1t,
    const float* __restrict__ w2, unsigned short* __restrict__ w2t)
{
  if (blockIdx.x < 64) {
    int t = blockIdx.x * 256 + threadIdx.x;
    int lane = threadIdx.x & 63;
    int e = eid[t];
    int pos = 0;
#pragma unroll
    for (int k = 0; k < E_NUM; k++) {
      bool me = (e == k);
      unsigned long long m = __ballot(me);
      if (m == 0ull) continue;                       // wave-uniform
      int leader = __ffsll((unsigned long long)m) - 1;
      int cw = __popcll(m);
      int base = 0;
      if (lane == leader) base = atomicAdd(&cnt[k * CSTRIDE], cw);
      base = __shfl(base, leader, 64);
      if (me) pos = base + __popcll(m & ((1ull << lane) - 1ull));
    }
    tokp[e * N_TOK + pos] = t;
    return;
  }

  // ---- transpose-convert fp32 [E][R][C] -> bf16 [E][C][R], 64x64 tiles ----
  int bid = blockIdx.x - 64;           // 0..1023
  const float* in; unsigned short* out; int R, C;
  if (bid < 512) { in = w1; out = w1t; R = D_DIM; C = H_DIM; }
  else           { in = w2; out = w2t; R = H_DIM; C = D_DIM; bid -= 512; }
  int rt = R / 64, ct = C / 64;
  int e = bid / (rt * ct);
  int rem = bid % (rt * ct);
  int r0 = (rem / ct) * 64, c0 = (rem % ct) * 64;
  __shared__ float tile[64][65];
  int tx = threadIdx.x & 63, ty = threadIdx.x >> 6;   // ty 0..3
  const float* src = in + (size_t)e * R * C;
#pragma unroll
  for (int i = 0; i < 16; i++)
    tile[ty + 4 * i][tx] = src[(size_t)(r0 + ty + 4 * i) * C + c0 + tx];
  __syncthreads();
  unsigned short* dst = out + (size_t)e * R * C;
#pragma unroll
  for (int i = 0; i < 16; i++)
    dst[(size_t)(c0 + ty + 4 * i) * R + r0 + tx] = f2bf(tile[tx][ty + 4 * i]);
}

// ---- per-block tile->expert mapping derived from the 8 counts --------------
__device__ __forceinline__ void tile_map(const int* __restrict__ cnt, int mt,
                                         int& e, int& loc, int& ccnt) {
  int tb = 0; e = 0; loc = -1; ccnt = 0;
#pragma unroll
  for (int k = 0; k < E_NUM; k++) {
    int ck = cnt[k * CSTRIDE];
    int ntk = (ck + BM - 1) >> 7;
    if (mt >= tb && mt < tb + ntk) { e = k; loc = (mt - tb) * BM; ccnt = ck; }
    tb += ntk;
  }
}

// ---------------- GEMM1: h = gelu(xhat_gathered @ W1t^T + b1), bf16 out ------
// 128x64 tile, BK=64, swizzle + DMA dbuf, 48KB LDS -> 3 blocks/CU.
__global__ __launch_bounds__(256) void smoe_gemm1(
    const unsigned short* __restrict__ xhat,   // [N][D]
    const unsigned short* __restrict__ w1t,    // [E][H][D]
    const float* __restrict__ b1,              // [E][H]
    const int* __restrict__ cnt,
    const int* __restrict__ tokp,              // [E][N_TOK]
    unsigned short* __restrict__ hbuf)         // [MP][H]
{
  int mt = blockIdx.x;
  int e, loc, ccnt;
  tile_map(cnt, mt, e, loc, ccnt);
  if (loc < 0) return;
  int nt = blockIdx.y;                 // 0..3 over H
  int tid = threadIdx.x;
  __shared__ unsigned short As[2][BM * BKG];    // 2 x 16 KB
  __shared__ unsigned short Bs[2][BN1 * BKG];   // 2 x 8 KB

  int r8 = tid >> 3;                   // 0..31
  int c8 = tid & 7;
  int slot = c8 ^ (r8 & 7);            // inverse-swizzled source slot

  const unsigned short* asrc[4];
#pragma unroll
  for (int j = 0; j < 4; j++) {
    int rl = loc + r8 + 32 * j;
    int tok = rl < ccnt ? tokp[e * N_TOK + rl] : 0;
    asrc[j] = xhat + (size_t)tok * D_DIM + slot * 8;
  }
  const unsigned short* bsrc[2];
#pragma unroll
  for (int j = 0; j < 2; j++)
    bsrc[j] = w1t + (size_t)e * H_DIM * D_DIM
            + (size_t)(nt * BN1 + r8 + 32 * j) * D_DIM + slot * 8;

  int wave = tid >> 6, lane = tid & 63;
  int wr = (wave >> 1) * 64;
  int wc = (wave & 1) * 32;
  int qm = lane & 15, quad = lane >> 4;

  int arow[4], brow[2], soff[2];
#pragma unroll
  for (int mi = 0; mi < 4; mi++) arow[mi] = (wr + mi * 16 + qm) * BKG;
#pragma unroll
  for (int ni = 0; ni < 2; ni++) brow[ni] = (wc + ni * 16 + qm) * BKG;
#pragma unroll
  for (int kk = 0; kk < 2; kk++) soff[kk] = ((kk * 4 + quad) ^ (qm & 7)) * 8;

  f32x4 acc[4][2] = {};
  int cur = 0;

#pragma unroll
  for (int j = 0; j < 4; j++) gl_lds16(asrc[j], &As[0][j * 2048 + tid * 8]);
#pragma unroll
  for (int j = 0; j < 2; j++) gl_lds16(bsrc[j], &Bs[0][j * 2048 + tid * 8]);
  __syncthreads();

  for (int t = 0; t < D_DIM / BKG; ++t) {       // 16 steps
    if (t + 1 < D_DIM / BKG) {
      int k0 = (t + 1) * BKG;
      int nb = cur ^ 1;
#pragma unroll
      for (int j = 0; j < 4; j++) gl_lds16(asrc[j] + k0, &As[nb][j * 2048 + tid * 8]);
#pragma unroll
      for (int j = 0; j < 2; j++) gl_lds16(bsrc[j] + k0, &Bs[nb][j * 2048 + tid * 8]);
    }
    bf16x8 af[2][4], bfr[2][2];
#pragma unroll
    for (int kk = 0; kk < 2; kk++) {
#pragma unroll
      for (int mi = 0; mi < 4; mi++)
        af[kk][mi] = *(const bf16x8*)&As[cur][arow[mi] + soff[kk]];
#pragma unroll
      for (int ni = 0; ni < 2; ni++)
        bfr[kk][ni] = *(const bf16x8*)&Bs[cur][brow[ni] + soff[kk]];
    }
#pragma unroll
    for (int kk = 0; kk < 2; kk++)
#pragma unroll
      for (int mi = 0; mi < 4; mi++)
#pragma unroll
        for (int ni = 0; ni < 2; ni++)
          acc[mi][ni] = __builtin_amdgcn_mfma_f32_16x16x32_bf16(
              af[kk][mi], bfr[kk][ni], acc[mi][ni], 0, 0, 0);
    __syncthreads();
    cur ^= 1;
  }

  int mbase = mt * BM;
#pragma unroll
  for (int ni = 0; ni < 2; ni++) {
    int col = nt * BN1 + wc + ni * 16 + qm;
    float bias = b1[e * H_DIM + col];
#pragma unroll
    for (int mi = 0; mi < 4; mi++) {
      int rl = wr + mi * 16 + quad * 4;
#pragma unroll
      for (int i = 0; i < 4; i++) {
        float g = gelu_exact_fast(acc[mi][ni][i] + bias);
        hbuf[(size_t)(mbase + rl + i) * H_DIM + col] = f2bf(g);
      }
    }
  }
}

// ---------------- GEMM2: y[tok] = h @ W2t^T + b2, fp32 scatter ----------------
// 128x64 tile (was 128x128): 48KB LDS -> 3 blocks/CU, grid (136,16)=2176.
__global__ __launch_bounds__(256) void smoe_gemm2(
    const unsigned short* __restrict__ hbuf,   // [MP][H]
    const unsigned short* __restrict__ w2t,    // [E][D][H]
    const float* __restrict__ b2,              // [E][D]
    const int* __restrict__ cnt,
    const int* __restrict__ tokp,              // [E][N_TOK]
    float* __restrict__ y)                     // [N][D]
{
  int mt = blockIdx.x;
  int e, loc, ccnt;
  tile_map(cnt, mt, e, loc, ccnt);
  if (loc < 0) return;
  int nt = blockIdx.y;                 // 0..15 over D
  int tid = threadIdx.x;
  __shared__ unsigned short As[2][BM * BKG];    // 2 x 16 KB
  __shared__ unsigned short Bs[2][BN2 * BKG];   // 2 x 8 KB  (48 KB total)

  int r8 = tid >> 3;
  int c8 = tid & 7;
  int slot = c8 ^ (r8 & 7);

  const unsigned short* asrc[4];
#pragma unroll
  for (int j = 0; j < 4; j++)
    asrc[j] = hbuf + (size_t)(mt * BM + r8 + 32 * j) * H_DIM + slot * 8;
  const unsigned short* bsrc[2];
#pragma unroll
  for (int j = 0; j < 2; j++)
    bsrc[j] = w2t + (size_t)e * D_DIM * H_DIM
            + (size_t)(nt * BN2 + r8 + 32 * j) * H_DIM + slot * 8;

  int wave = tid >> 6, lane = tid & 63;
  int wr = (wave >> 1) * 64;
  int wc = (wave & 1) * 32;
  int qm = lane & 15, quad = lane >> 4;

  int arow[4], brow[2], soff[2];
#pragma unroll
  for (int mi = 0; mi < 4; mi++) arow[mi] = (wr + mi * 16 + qm) * BKG;
#pragma unroll
  for (int ni = 0; ni < 2; ni++) brow[ni] = (wc + ni * 16 + qm) * BKG;
#pragma unroll
  for (int kk = 0; kk < 2; kk++) soff[kk] = ((kk * 4 + quad) ^ (qm & 7)) * 8;

  f32x4 acc[4][2] = {};
  int cur = 0;

#pragma unroll
  for (int j = 0; j < 4; j++) gl_lds16(asrc[j], &As[0][j * 2048 + tid * 8]);
#pragma unroll
  for (int j = 0; j < 2; j++) gl_lds16(bsrc[j], &Bs[0][j * 2048 + tid * 8]);
  __syncthreads();

  for (int t = 0; t < H_DIM / BKG; ++t) {       // 4 steps
    if (t + 1 < H_DIM / BKG) {
      int k0 = (t + 1) * BKG;
      int nb = cur ^ 1;
#pragma unroll
      for (int j = 0; j < 4; j++) gl_lds16(asrc[j] + k0, &As[nb][j * 2048 + tid * 8]);
#pragma unroll
      for (int j = 0; j < 2; j++) gl_lds16(bsrc[j] + k0, &Bs[nb][j * 2048 + tid * 8]);
    }
    bf16x8 af[2][4], bfr[2][2];
#pragma unroll
    for (int kk = 0; kk < 2; kk++) {
#pragma unroll
      for (int mi = 0; mi < 4; mi++)
        af[kk][mi] = *(const bf16x8*)&As[cur][arow[mi] + soff[kk]];
#pragma unroll
      for (int ni = 0; ni < 2; ni++)
        bfr[kk][ni] = *(const bf16x8*)&Bs[cur][brow[ni] + soff[kk]];
    }
#pragma unroll
    for (int kk = 0; kk < 2; kk++)
#pragma unroll
      for (int mi = 0; mi < 4; mi++)
#pragma unroll
        for (int ni = 0; ni < 2; ni++)
          acc[mi][ni] = __builtin_amdgcn_mfma_f32_16x16x32_bf16(
              af[kk][mi], bfr[kk][ni], acc[mi][ni], 0, 0, 0);
    __syncthreads();
    cur ^= 1;
  }

#pragma unroll
  for (int mi = 0; mi < 4; mi++) {
#pragma unroll
    for (int i = 0; i < 4; i++) {
      int rl = loc + wr + mi * 16 + quad * 4 + i;
      if (rl >= ccnt) continue;
      int tok = tokp[e * N_TOK + rl];
#pragma unroll
      for (int ni = 0; ni < 2; ni++) {
        int col = nt * BN2 + wc + ni * 16 + qm;
        y[(size_t)tok * D_DIM + col] = acc[mi][ni][i] + b2[e * D_DIM + col];
      }
    }
  }
}

extern "C" void kernel_launch(void* const* d_in, const int* in_sizes, int n_in,
                              void* d_out, int out_size, void* d_ws, size_t ws_size,
                              hipStream_t stream) {
  (void)in_sizes; (void)n_in; (void)out_size; (void)ws_size;
  const float* x    = (const float*)d_in[0];
  const float* wg   = (const float*)d_in[1];
  const float* ln_s = (const float*)d_in[2];
  const float* ln_b = (const float*)d_in[3];
  const float* w1   = (const float*)d_in[4];
  const float* b1   = (const float*)d_in[5];
  const float* w2   = (const float*)d_in[6];
  const float* b2   = (const float*)d_in[7];
  float* y = (float*)d_out;

  char* ws = (char*)d_ws;
  size_t off = 0;
  auto alloc = [&](size_t bytes) {
    void* p = ws + off;
    off = (off + bytes + 255) & ~(size_t)255;
    return p;
  };
  unsigned short* xhat = (unsigned short*)alloc((size_t)N_TOK * D_DIM * 2);          // 32 MB
  unsigned short* w1t  = (unsigned short*)alloc((size_t)E_NUM * D_DIM * H_DIM * 2);  // 4 MB
  unsigned short* w2t  = (unsigned short*)alloc((size_t)E_NUM * D_DIM * H_DIM * 2);  // 4 MB
  unsigned short* hbuf = (unsigned short*)alloc((size_t)MP * H_DIM * 2);             // 8.5 MB
  int* eid    = (int*)alloc((size_t)N_TOK * 4);
  int* tokp   = (int*)alloc((size_t)E_NUM * N_TOK * 4);                              // 512 KB
  int* cnt    = (int*)alloc((size_t)E_NUM * CSTRIDE * 4);                            // 512 B

  hipMemsetAsync(cnt, 0, (size_t)E_NUM * CSTRIDE * 4, stream);
  smoe_gate<<<N_TOK / 4, 256, 0, stream>>>(x, wg, ln_s, ln_b, xhat, eid);
  smoe_scatter_cvt<<<64 + 1024, 256, 0, stream>>>(eid, cnt, tokp, w1, w1t, w2, w2t);
  smoe_gemm1<<<dim3(MAXTILES, H_DIM / BN1), 256, 0, stream>>>(xhat, w1t, b1, cnt, tokp, hbuf);
  smoe_gemm2<<<dim3(MAXTILES, D_DIM / BN2), 256, 0, stream>>>(hbuf, w2t, b2, cnt, tokp, y);
}

// Round 11
// 209.070 us; speedup vs baseline: 1.0763x; 1.0161x over previous
//
#include <hip/hip_runtime.h>
#include <math.h>

#define N_TOK 16384
#define D_DIM 1024
#define E_NUM 8
#define H_DIM 256
#define LN_EPS 1e-5f

#define BM 128
#define BN1 64           /* N-tile GEMM1 (48KB LDS -> 3 blocks/CU) */
#define BN2 64           /* N-tile GEMM2 (48KB LDS -> 3 blocks/CU) */
#define BKG 64           /* K-tile for both GEMMs */
#define MAXTILES (N_TOK / BM + E_NUM)   /* 136 = 17 * 8 XCDs (bijective swizzle) */
#define MP (MAXTILES * BM)              /* 17408 */
#define CSTRIDE 16       /* cnt[k*CSTRIDE]: 64 B apart -> separate L2 lines */

typedef __attribute__((ext_vector_type(8))) short bf16x8;
typedef __attribute__((ext_vector_type(4))) float f32x4;

__device__ __forceinline__ unsigned short f2bf(float f) {
  union { float f; unsigned u; } cv; cv.f = f;
  unsigned u = cv.u;
  u += 0x7fffu + ((u >> 16) & 1u);   // round-to-nearest-even
  return (unsigned short)(u >> 16);
}

__device__ __forceinline__ void gl_lds16(const void* g, void* l) {
  __builtin_amdgcn_global_load_lds(
      (const __attribute__((address_space(1))) unsigned int*)g,
      (__attribute__((address_space(3))) unsigned int*)l, 16, 0, 0);
}

// fast erf via Abramowitz-Stegun 7.1.26 (|err| <= 1.5e-7) + hw exp.
__device__ __forceinline__ float gelu_exact_fast(float v) {
  float u = fabsf(v) * 0.70710678118654752f;
  float t = 1.0f / (1.0f + 0.3275911f * u);
  float poly = t * (0.254829592f + t * (-0.284496736f + t * (1.421413741f
             + t * (-1.453152027f + t * 1.061405429f))));
  float er = 1.0f - poly * __expf(-u * u);
  er = v >= 0.0f ? er : -er;
  return 0.5f * v * (1.0f + er);
}

// ---- VALU cross-lane transport (DPP) + verified ds_swizzle patterns --------
template <int CTRL>
__device__ __forceinline__ int dppi(int x) {
  return __builtin_amdgcn_update_dpp(0, x, CTRL, 0xf, 0xf, true);
}
template <int CTRL>
__device__ __forceinline__ double dppd(double x) {
  union { double d; int i[2]; } u; u.d = x;
  u.i[0] = dppi<CTRL>(u.i[0]);
  u.i[1] = dppi<CTRL>(u.i[1]);
  return u.d;
}
template <int CTRL>
__device__ __forceinline__ float dppf(float x) {
  union { float f; int i; } u; u.f = x;
  u.i = dppi<CTRL>(u.i);
  return u.f;
}
template <int IMM>
__device__ __forceinline__ double swzd(double x) {
  union { double d; int i[2]; } u; u.d = x;
  u.i[0] = __builtin_amdgcn_ds_swizzle(u.i[0], IMM);
  u.i[1] = __builtin_amdgcn_ds_swizzle(u.i[1], IMM);
  return u.d;
}
template <int IMM>
__device__ __forceinline__ float swzf(float x) {
  union { float f; int i; } u; u.f = x;
  u.i = __builtin_amdgcn_ds_swizzle(u.i, IMM);
  return u.f;
}

// ---------------- gate: ONE WAVE PER TOKEN (round-8 proven, 64 VGPR) ---------
__global__ __launch_bounds__(256) void smoe_gate(
    const float* __restrict__ x, const float* __restrict__ wg,
    const float* __restrict__ ln_s, const float* __restrict__ ln_b,
    unsigned short* __restrict__ xhat, int* __restrict__ eid)
{
  int lane = threadIdx.x & 63, wave = threadIdx.x >> 6;
  int t = blockIdx.x * 4 + wave;

  const float4* x4 = (const float4*)x + (size_t)t * 256;
  float4 v[4];
  float s = 0.f, ss = 0.f;
#pragma unroll
  for (int j = 0; j < 4; j++) {
    v[j] = x4[lane + 64 * j];
    s  += v[j].x + v[j].y + v[j].z + v[j].w;
    ss += v[j].x * v[j].x + v[j].y * v[j].y + v[j].z * v[j].z + v[j].w * v[j].w;
  }
  const float4* wg4 = (const float4*)wg;
  double lg[E_NUM];
#pragma unroll
  for (int e = 0; e < E_NUM; e++) {
    double acc = 0.0;
#pragma unroll
    for (int j = 0; j < 4; j++) {
      float4 w = wg4[e * 256 + lane + 64 * j];
      acc += (double)v[j].x * w.x + (double)v[j].y * w.y
           + (double)v[j].z * w.z + (double)v[j].w * w.w;
    }
    lg[e] = acc;
  }

  double a0, a1, a2, a3;
  {
    double p0 = dppd<0xB1>(lg[0]), p1 = dppd<0xB1>(lg[1]);
    double p2 = dppd<0xB1>(lg[2]), p3 = dppd<0xB1>(lg[3]);
    double p4 = dppd<0xB1>(lg[4]), p5 = dppd<0xB1>(lg[5]);
    double p6 = dppd<0xB1>(lg[6]), p7 = dppd<0xB1>(lg[7]);
    bool b = lane & 1;
    a0 = b ? lg[1] + p1 : lg[0] + p0;
    a1 = b ? lg[3] + p3 : lg[2] + p2;
    a2 = b ? lg[5] + p5 : lg[4] + p4;
    a3 = b ? lg[7] + p7 : lg[6] + p6;
  }
  double c0, c1;
  {
    double q0 = dppd<0x4E>(a0), q1 = dppd<0x4E>(a1);
    double q2 = dppd<0x4E>(a2), q3 = dppd<0x4E>(a3);
    bool b = (lane >> 1) & 1;
    c0 = b ? a1 + q1 : a0 + q0;
    c1 = b ? a3 + q3 : a2 + q2;
  }
  double c;
  {
    double r0 = swzd<0x101F>(c0), r1 = swzd<0x101F>(c1);   // TRUE xor4
    bool b = (lane >> 2) & 1;
    c = b ? c1 + r1 : c0 + r0;
  }
  c += dppd<0x128>(c);          // xor8
  c += swzd<0x401F>(c);         // xor16
  c += __shfl_xor(c, 32, 64);   // xor32

  double val = c; int idx = lane & 7;
  {
    double ov = dppd<0xB1>(val); int oi = dppi<0xB1>(idx);
    if (ov > val || (ov == val && oi < idx)) { val = ov; idx = oi; }
  }
  {
    double ov = dppd<0x4E>(val); int oi = dppi<0x4E>(idx);
    if (ov > val || (ov == val && oi < idx)) { val = ov; idx = oi; }
  }
  {
    double ov = dppd<0x124>(val); int oi = dppi<0x124>(idx);
    if (ov > val || (ov == val && oi < idx)) { val = ov; idx = oi; }
  }
  int best = idx;

  s += dppf<0xB1>(s);   ss += dppf<0xB1>(ss);
  s += dppf<0x4E>(s);   ss += dppf<0x4E>(ss);
  s += dppf<0x141>(s);  ss += dppf<0x141>(ss);
  s += dppf<0x128>(s);  ss += dppf<0x128>(ss);
  s += swzf<0x401F>(s); ss += swzf<0x401F>(ss);
  s += __shfl_xor(s, 32, 64);
  ss += __shfl_xor(ss, 32, 64);

  float mean = s * (1.0f / (float)D_DIM);
  float var  = ss * (1.0f / (float)D_DIM) - mean * mean;
  float rstd = 1.0f / sqrtf(var + LN_EPS);

  if (lane == 0) eid[t] = best;

  const float4* s4 = (const float4*)(ln_s + (size_t)best * D_DIM);
  const float4* b4 = (const float4*)(ln_b + (size_t)best * D_DIM);
  ushort4* xo = (ushort4*)(xhat + (size_t)t * D_DIM);
#pragma unroll
  for (int j = 0; j < 4; j++) {
    float4 sc = s4[lane + 64 * j], bi = b4[lane + 64 * j];
    ushort4 o;
    o.x = f2bf((v[j].x - mean) * rstd * sc.x + bi.x);
    o.y = f2bf((v[j].y - mean) * rstd * sc.y + bi.y);
    o.z = f2bf((v[j].z - mean) * rstd * sc.z + bi.z);
    o.w = f2bf((v[j].w - mean) * rstd * sc.w + bi.w);
    xo[lane + 64 * j] = o;
  }
}

// ---------------- scatter (blocks 0..63) + weight cvt (blocks 64..1087) -------
__global__ __launch_bounds__(256) void smoe_scatter_cvt(
    const int* __restrict__ eid, int* __restrict__ cnt, int* __restrict__ tokp,
    const float* __restrict__ w1, unsigned short* __restrict__ w1t,
    const float* __restrict__ w2, unsigned short* __restrict__ w2t)
{
  if (blockIdx.x < 64) {
    int t = blockIdx.x * 256 + threadIdx.x;
    int lane = threadIdx.x & 63;
    int e = eid[t];
    int pos = 0;
#pragma unroll
    for (int k = 0; k < E_NUM; k++) {
      bool me = (e == k);
      unsigned long long m = __ballot(me);
      if (m == 0ull) continue;                       // wave-uniform
      int leader = __ffsll((unsigned long long)m) - 1;
      int cw = __popcll(m);
      int base = 0;
      if (lane == leader) base = atomicAdd(&cnt[k * CSTRIDE], cw);
      base = __shfl(base, leader, 64);
      if (me) pos = base + __popcll(m & ((1ull << lane) - 1ull));
    }
    tokp[e * N_TOK + pos] = t;
    return;
  }

  // ---- transpose-convert fp32 [E][R][C] -> bf16 [E][C][R], 64x64 tiles ----
  int bid = blockIdx.x - 64;           // 0..1023
  const float* in; unsigned short* out; int R, C;
  if (bid < 512) { in = w1; out = w1t; R = D_DIM; C = H_DIM; }
  else           { in = w2; out = w2t; R = H_DIM; C = D_DIM; bid -= 512; }
  int rt = R / 64, ct = C / 64;
  int e = bid / (rt * ct);
  int rem = bid % (rt * ct);
  int r0 = (rem / ct) * 64, c0 = (rem % ct) * 64;
  __shared__ float tile[64][65];
  int tx = threadIdx.x & 63, ty = threadIdx.x >> 6;   // ty 0..3
  const float* src = in + (size_t)e * R * C;
#pragma unroll
  for (int i = 0; i < 16; i++)
    tile[ty + 4 * i][tx] = src[(size_t)(r0 + ty + 4 * i) * C + c0 + tx];
  __syncthreads();
  unsigned short* dst = out + (size_t)e * R * C;
#pragma unroll
  for (int i = 0; i < 16; i++)
    dst[(size_t)(c0 + ty + 4 * i) * R + r0 + tx] = f2bf(tile[tx][ty + 4 * i]);
}

// ---- per-block tile->expert mapping derived from the 8 counts --------------
__device__ __forceinline__ void tile_map(const int* __restrict__ cnt, int mt,
                                         int& e, int& loc, int& ccnt) {
  int tb = 0; e = 0; loc = -1; ccnt = 0;
#pragma unroll
  for (int k = 0; k < E_NUM; k++) {
    int ck = cnt[k * CSTRIDE];
    int ntk = (ck + BM - 1) >> 7;
    if (mt >= tb && mt < tb + ntk) { e = k; loc = (mt - tb) * BM; ccnt = ck; }
    tb += ntk;
  }
}

// ---------------- GEMM1: h = gelu(xhat_gathered @ W1t^T + b1), bf16 out ------
// 1D grid, XCD-co-locating swizzle: all 4 nt-blocks of an mt land on ONE XCD
// so the A-tile (xhat rows) is fetched into exactly one L2 (T1 variant).
__global__ __launch_bounds__(256) void smoe_gemm1(
    const unsigned short* __restrict__ xhat,   // [N][D]
    const unsigned short* __restrict__ w1t,    // [E][H][D]
    const float* __restrict__ b1,              // [E][H]
    const int* __restrict__ cnt,
    const int* __restrict__ tokp,              // [E][N_TOK]
    unsigned short* __restrict__ hbuf)         // [MP][H]
{
  int bid = blockIdx.x;                // 544 = 8 XCD * 17 mt * 4 nt
  int xcd = bid & 7, i = bid >> 3;
  int nt = i & 3;                      // 0..3 over H
  int mt = (i >> 2) * 8 + xcd;         // 0..135; same-mt blocks share XCD
  int e, loc, ccnt;
  tile_map(cnt, mt, e, loc, ccnt);
  if (loc < 0) return;
  int tid = threadIdx.x;
  __shared__ unsigned short As[2][BM * BKG];    // 2 x 16 KB
  __shared__ unsigned short Bs[2][BN1 * BKG];   // 2 x 8 KB

  int r8 = tid >> 3;                   // 0..31
  int c8 = tid & 7;
  int slot = c8 ^ (r8 & 7);            // inverse-swizzled source slot

  const unsigned short* asrc[4];
#pragma unroll
  for (int j = 0; j < 4; j++) {
    int rl = loc + r8 + 32 * j;
    int tok = rl < ccnt ? tokp[e * N_TOK + rl] : 0;
    asrc[j] = xhat + (size_t)tok * D_DIM + slot * 8;
  }
  const unsigned short* bsrc[2];
#pragma unroll
  for (int j = 0; j < 2; j++)
    bsrc[j] = w1t + (size_t)e * H_DIM * D_DIM
            + (size_t)(nt * BN1 + r8 + 32 * j) * D_DIM + slot * 8;

  int wave = tid >> 6, lane = tid & 63;
  int wr = (wave >> 1) * 64;
  int wc = (wave & 1) * 32;
  int qm = lane & 15, quad = lane >> 4;

  int arow[4], brow[2], soff[2];
#pragma unroll
  for (int mi = 0; mi < 4; mi++) arow[mi] = (wr + mi * 16 + qm) * BKG;
#pragma unroll
  for (int ni = 0; ni < 2; ni++) brow[ni] = (wc + ni * 16 + qm) * BKG;
#pragma unroll
  for (int kk = 0; kk < 2; kk++) soff[kk] = ((kk * 4 + quad) ^ (qm & 7)) * 8;

  f32x4 acc[4][2] = {};
  int cur = 0;

#pragma unroll
  for (int j = 0; j < 4; j++) gl_lds16(asrc[j], &As[0][j * 2048 + tid * 8]);
#pragma unroll
  for (int j = 0; j < 2; j++) gl_lds16(bsrc[j], &Bs[0][j * 2048 + tid * 8]);
  __syncthreads();

  for (int t = 0; t < D_DIM / BKG; ++t) {       // 16 steps
    if (t + 1 < D_DIM / BKG) {
      int k0 = (t + 1) * BKG;
      int nb = cur ^ 1;
#pragma unroll
      for (int j = 0; j < 4; j++) gl_lds16(asrc[j] + k0, &As[nb][j * 2048 + tid * 8]);
#pragma unroll
      for (int j = 0; j < 2; j++) gl_lds16(bsrc[j] + k0, &Bs[nb][j * 2048 + tid * 8]);
    }
    bf16x8 af[2][4], bfr[2][2];
#pragma unroll
    for (int kk = 0; kk < 2; kk++) {
#pragma unroll
      for (int mi = 0; mi < 4; mi++)
        af[kk][mi] = *(const bf16x8*)&As[cur][arow[mi] + soff[kk]];
#pragma unroll
      for (int ni = 0; ni < 2; ni++)
        bfr[kk][ni] = *(const bf16x8*)&Bs[cur][brow[ni] + soff[kk]];
    }
#pragma unroll
    for (int kk = 0; kk < 2; kk++)
#pragma unroll
      for (int mi = 0; mi < 4; mi++)
#pragma unroll
        for (int ni = 0; ni < 2; ni++)
          acc[mi][ni] = __builtin_amdgcn_mfma_f32_16x16x32_bf16(
              af[kk][mi], bfr[kk][ni], acc[mi][ni], 0, 0, 0);
    __syncthreads();
    cur ^= 1;
  }

  int mbase = mt * BM;
#pragma unroll
  for (int ni = 0; ni < 2; ni++) {
    int col = nt * BN1 + wc + ni * 16 + qm;
    float bias = b1[e * H_DIM + col];
#pragma unroll
    for (int mi = 0; mi < 4; mi++) {
      int rl = wr + mi * 16 + quad * 4;
#pragma unroll
      for (int i2 = 0; i2 < 4; i2++) {
        float g = gelu_exact_fast(acc[mi][ni][i2] + bias);
        hbuf[(size_t)(mbase + rl + i2) * H_DIM + col] = f2bf(g);
      }
    }
  }
}

// ---------------- GEMM2: y[tok] = h @ W2t^T + b2, fp32 scatter ----------------
// 1D grid, XCD-co-locating swizzle: all 16 nt-blocks of an mt on ONE XCD so
// the hbuf A-tile is fetched into exactly one L2.
__global__ __launch_bounds__(256) void smoe_gemm2(
    const unsigned short* __restrict__ hbuf,   // [MP][H]
    const unsigned short* __restrict__ w2t,    // [E][D][H]
    const float* __restrict__ b2,              // [E][D]
    const int* __restrict__ cnt,
    const int* __restrict__ tokp,              // [E][N_TOK]
    float* __restrict__ y)                     // [N][D]
{
  int bid = blockIdx.x;                // 2176 = 8 XCD * 17 mt * 16 nt
  int xcd = bid & 7, i = bid >> 3;
  int nt = i & 15;                     // 0..15 over D
  int mt = (i >> 4) * 8 + xcd;         // 0..135
  int e, loc, ccnt;
  tile_map(cnt, mt, e, loc, ccnt);
  if (loc < 0) return;
  int tid = threadIdx.x;
  __shared__ unsigned short As[2][BM * BKG];    // 2 x 16 KB
  __shared__ unsigned short Bs[2][BN2 * BKG];   // 2 x 8 KB  (48 KB total)

  int r8 = tid >> 3;
  int c8 = tid & 7;
  int slot = c8 ^ (r8 & 7);

  const unsigned short* asrc[4];
#pragma unroll
  for (int j = 0; j < 4; j++)
    asrc[j] = hbuf + (size_t)(mt * BM + r8 + 32 * j) * H_DIM + slot * 8;
  const unsigned short* bsrc[2];
#pragma unroll
  for (int j = 0; j < 2; j++)
    bsrc[j] = w2t + (size_t)e * D_DIM * H_DIM
            + (size_t)(nt * BN2 + r8 + 32 * j) * H_DIM + slot * 8;

  int wave = tid >> 6, lane = tid & 63;
  int wr = (wave >> 1) * 64;
  int wc = (wave & 1) * 32;
  int qm = lane & 15, quad = lane >> 4;

  int arow[4], brow[2], soff[2];
#pragma unroll
  for (int mi = 0; mi < 4; mi++) arow[mi] = (wr + mi * 16 + qm) * BKG;
#pragma unroll
  for (int ni = 0; ni < 2; ni++) brow[ni] = (wc + ni * 16 + qm) * BKG;
#pragma unroll
  for (int kk = 0; kk < 2; kk++) soff[kk] = ((kk * 4 + quad) ^ (qm & 7)) * 8;

  f32x4 acc[4][2] = {};
  int cur = 0;

#pragma unroll
  for (int j = 0; j < 4; j++) gl_lds16(asrc[j], &As[0][j * 2048 + tid * 8]);
#pragma unroll
  for (int j = 0; j < 2; j++) gl_lds16(bsrc[j], &Bs[0][j * 2048 + tid * 8]);
  __syncthreads();

  for (int t = 0; t < H_DIM / BKG; ++t) {       // 4 steps
    if (t + 1 < H_DIM / BKG) {
      int k0 = (t + 1) * BKG;
      int nb = cur ^ 1;
#pragma unroll
      for (int j = 0; j < 4; j++) gl_lds16(asrc[j] + k0, &As[nb][j * 2048 + tid * 8]);
#pragma unroll
      for (int j = 0; j < 2; j++) gl_lds16(bsrc[j] + k0, &Bs[nb][j * 2048 + tid * 8]);
    }
    bf16x8 af[2][4], bfr[2][2];
#pragma unroll
    for (int kk = 0; kk < 2; kk++) {
#pragma unroll
      for (int mi = 0; mi < 4; mi++)
        af[kk][mi] = *(const bf16x8*)&As[cur][arow[mi] + soff[kk]];
#pragma unroll
      for (int ni = 0; ni < 2; ni++)
        bfr[kk][ni] = *(const bf16x8*)&Bs[cur][brow[ni] + soff[kk]];
    }
#pragma unroll
    for (int kk = 0; kk < 2; kk++)
#pragma unroll
      for (int mi = 0; mi < 4; mi++)
#pragma unroll
        for (int ni = 0; ni < 2; ni++)
          acc[mi][ni] = __builtin_amdgcn_mfma_f32_16x16x32_bf16(
              af[kk][mi], bfr[kk][ni], acc[mi][ni], 0, 0, 0);
    __syncthreads();
    cur ^= 1;
  }

#pragma unroll
  for (int mi = 0; mi < 4; mi++) {
#pragma unroll
    for (int i2 = 0; i2 < 4; i2++) {
      int rl = loc + wr + mi * 16 + quad * 4 + i2;
      if (rl >= ccnt) continue;
      int tok = tokp[e * N_TOK + rl];
#pragma unroll
      for (int ni = 0; ni < 2; ni++) {
        int col = nt * BN2 + wc + ni * 16 + qm;
        y[(size_t)tok * D_DIM + col] = acc[mi][ni][i2] + b2[e * D_DIM + col];
      }
    }
  }
}

extern "C" void kernel_launch(void* const* d_in, const int* in_sizes, int n_in,
                              void* d_out, int out_size, void* d_ws, size_t ws_size,
                              hipStream_t stream) {
  (void)in_sizes; (void)n_in; (void)out_size; (void)ws_size;
  const float* x    = (const float*)d_in[0];
  const float* wg   = (const float*)d_in[1];
  const float* ln_s = (const float*)d_in[2];
  const float* ln_b = (const float*)d_in[3];
  const float* w1   = (const float*)d_in[4];
  const float* b1   = (const float*)d_in[5];
  const float* w2   = (const float*)d_in[6];
  const float* b2   = (const float*)d_in[7];
  float* y = (float*)d_out;

  char* ws = (char*)d_ws;
  size_t off = 0;
  auto alloc = [&](size_t bytes) {
    void* p = ws + off;
    off = (off + bytes + 255) & ~(size_t)255;
    return p;
  };
  unsigned short* xhat = (unsigned short*)alloc((size_t)N_TOK * D_DIM * 2);          // 32 MB
  unsigned short* w1t  = (unsigned short*)alloc((size_t)E_NUM * D_DIM * H_DIM * 2);  // 4 MB
  unsigned short* w2t  = (unsigned short*)alloc((size_t)E_NUM * D_DIM * H_DIM * 2);  // 4 MB
  unsigned short* hbuf = (unsigned short*)alloc((size_t)MP * H_DIM * 2);             // 8.5 MB
  int* eid    = (int*)alloc((size_t)N_TOK * 4);
  int* tokp   = (int*)alloc((size_t)E_NUM * N_TOK * 4);                              // 512 KB
  int* cnt    = (int*)alloc((size_t)E_NUM * CSTRIDE * 4);                            // 512 B

  hipMemsetAsync(cnt, 0, (size_t)E_NUM * CSTRIDE * 4, stream);
  smoe_gate<<<N_TOK / 4, 256, 0, stream>>>(x, wg, ln_s, ln_b, xhat, eid);
  smoe_scatter_cvt<<<64 + 1024, 256, 0, stream>>>(eid, cnt, tokp, w1, w1t, w2, w2t);
  smoe_gemm1<<<MAXTILES * (H_DIM / BN1), 256, 0, stream>>>(xhat, w1t, b1, cnt, tokp, hbuf);
  smoe_gemm2<<<MAXTILES * (D_DIM / BN2), 256, 0, stream>>>(hbuf, w2t, b2, cnt, tokp, y);
}